// Round 10
// baseline (103.270 us; speedup 1.0000x reference)
//
#include <hip/hip_runtime.h>
#include <math.h>

#define HH 256
#define WW 256
#define VV 192
#define DD 256

// geometry (matches reference linspace(-sqrt2,sqrt2,256), DT = 2*sqrt2/256)
#define DSQ2      1.41421356237309504880
#define F_DT      ((float)(2.0 * DSQ2 / 256.0))
#define F_INV_DS  ((float)(255.0 / (2.0 * DSQ2)))        // 90.1562 index per world unit
#define F_DDY     ((float)(255.0 / (2.0 * DSQ2) / 128.0))// d/t index step per pixel row
#define F_SIG     ((float)(256.0 * DSQ2 / 255.0))        // 1.41976 px per index step
#define F_RAD     ((float)(128.0 * DSQ2))                // 181.0193

#define TPITCH 67        // 66 used cols + 1 pad
#define NSEG 16
#define NV (VV / NSEG)   // 12 views per bwd segment -> 12.3 KB LDS -> 8 blocks/CU

static __device__ __forceinline__ float view_angle(int v) {
    // matches np.linspace(0, pi, 192, endpoint=False): f64 mul then cast
    return (float)((double)v * (3.14159265358979323846 / 192.0));
}

// ---------------------------------------------------------------------------
// Kernel 0: sacc = 0 (786 KB only; out=input moved into fwd)
// ---------------------------------------------------------------------------
__global__ __launch_bounds__(256)
void init_kernel(float* __restrict__ sacc, int nsino4) {
    const int i = blockIdx.x * 256 + threadIdx.x;
    if (i < nsino4)
        ((float4*)sacc)[i] = make_float4(0.f, 0.f, 0.f, 0.f);
}

// ---------------------------------------------------------------------------
// Kernel 1: tile-local sample-driven forward projection.
// Block = (64x64 image tile, view, image). lane <-> d, waves <-> t phase.
// Tile + 1-px halo staged in LDS; branchless unroll-4 inner loop; per-thread
// guarded global atomicAdd epilogue. v==0 blocks also copy out = input.
// ---------------------------------------------------------------------------
__global__ __launch_bounds__(256)
void fwd_tile_kernel(const float* __restrict__ img_all,
                     float* __restrict__ sacc,
                     float* __restrict__ out,
                     int npix4) {
    __shared__ float tile[66 * TPITCH];
    const int tx = (blockIdx.x & 3) << 6;
    const int ty = (blockIdx.x >> 2) << 6;
    const int v  = blockIdx.y;
    const int b  = blockIdx.z;
    const int tid  = threadIdx.x;
    const int lane = tid & 63;
    const int wv   = tid >> 6;

    if (v == 0) {                                        // out = input, spread over 32 blocks
        const int chunk = (b << 4) + blockIdx.x;         // 0..nb*16-1, 1024 float4 each
        const float4* in4 = (const float4*)img_all;
        float4* o4 = (float4*)out;
#pragma unroll
        for (int k = 0; k < 4; ++k) {
            const int i = (chunk << 10) + (k << 8) + tid;
            if (i < npix4) o4[i] = in4[i];
        }
    }

    const float* __restrict__ img = img_all + (b << 16);

    // ---- stage 66x66 (global x,y in [tx-1, tx+64] x [ty-1, ty+64], 0 outside) ----
    for (int k = tid; k < 64 * 16; k += 256) {           // interior, float4
        const int r  = k >> 4;
        const int c4 = (k & 15) << 2;
        const float4 val = *(const float4*)(img + ((ty + r) << 8) + tx + c4);
        float* dst = tile + (r + 1) * TPITCH + 1 + c4;
        dst[0] = val.x; dst[1] = val.y; dst[2] = val.z; dst[3] = val.w;
    }
    if (tid < 132) {                                     // vertical halo cols (0, 65)
        const int r  = tid >> 1;
        const int cc = (tid & 1) ? 65 : 0;
        const int gx = tx - 1 + cc;
        const int gy = ty - 1 + r;
        float vv = 0.0f;
        if ((unsigned)gx < 256u && (unsigned)gy < 256u) vv = img[(gy << 8) + gx];
        tile[r * TPITCH + cc] = vv;
    }
    if (tid < 128) {                                     // horizontal halo rows (0, 65)
        const int cc = 1 + (tid & 63);
        const int r  = (tid >> 6) ? 65 : 0;
        const int gx = tx - 1 + cc;
        const int gy = ty - 1 + r;
        float vv = 0.0f;
        if ((unsigned)gx < 256u && (unsigned)gy < 256u) vv = img[(gy << 8) + gx];
        tile[r * TPITCH + cc] = vv;
    }

    // ---- geometry: pixel(d,t) = (X0 + d*Xd + t*Xt, Y0 + d*Yd + t*Yt) ----
    float sn, cs;
    sincosf(view_angle(v), &sn, &cs);
    const float Xd = -sn * F_SIG, Yd = cs * F_SIG;
    const float Xt =  cs * F_SIG, Yt = sn * F_SIG;
    const float X0 = 127.5f - F_RAD * (cs - sn);
    const float Y0 = 127.5f - F_RAD * (cs + sn);

    // ownership: ix0 in [tx+lox, tx+63] (edge tiles also own the -1 fringe)
    const int lox = (tx == 0) ? -1 : 0;
    const int loy = (ty == 0) ? -1 : 0;
    const unsigned spanx = (unsigned)(64 - lox);
    const unsigned spany = (unsigned)(64 - loy);

    // (d,t) bbox of owned pixel box via the inverse (orthogonal) map
    const float xwl = ((float)(tx + lox) + 0.5f) * (1.0f / 128.0f) - 1.0f;
    const float xwh = ((float)(tx + 64)  + 0.5f) * (1.0f / 128.0f) - 1.0f;
    const float ywl = ((float)(ty + loy) + 0.5f) * (1.0f / 128.0f) - 1.0f;
    const float ywh = ((float)(ty + 64)  + 0.5f) * (1.0f / 128.0f) - 1.0f;
    const float dA = -xwl * sn, dB = -xwh * sn;
    const float dC =  ywl * cs, dDq =  ywh * cs;
    const float tAq =  xwl * cs, tB =  xwh * cs;
    const float tC =  ywl * sn, tD =  ywh * sn;
    const float dcmin = 127.5f + (fminf(dA, dB) + fminf(dC, dDq)) * F_INV_DS;
    const float dcmax = 127.5f + (fmaxf(dA, dB) + fmaxf(dC, dDq)) * F_INV_DS;
    const float tcmin = 127.5f + (fminf(tAq, tB) + fminf(tC, tD)) * F_INV_DS;
    const float tcmax = 127.5f + (fmaxf(tAq, tB) + fmaxf(tC, tD)) * F_INV_DS;
    const int dlo = max(0, (int)ceilf(dcmin - 0.002f));
    const int dhi = min(255, (int)floorf(dcmax + 0.002f));
    const int tlo = max(0, (int)ceilf(tcmin - 0.002f));
    const int thi = min(255, (int)floorf(tcmax + 0.002f));

    __syncthreads();

    const int sbase = (b * VV + v) << 8;
    for (int dbase = dlo; dbase <= dhi; dbase += 64) {   // 1 iter except rare edge tiles
        const int d = dbase + lane;
        float acc = 0.0f;
        // tile-local coords shifted so floor(xc) == LDS col directly
        float xc = fmaf((float)d, Xd, fmaf((float)(tlo + wv), Xt, X0)) - (float)tx + 1.0f;
        float yc = fmaf((float)d, Yd, fmaf((float)(tlo + wv), Yt, Y0)) - (float)ty + 1.0f;
        const float step_x = 4.0f * Xt, step_y = 4.0f * Yt;
#pragma unroll 4
        for (int t = tlo + wv; t <= thi; t += 4) {
            const float xf = floorf(xc);
            const float yf = floorf(yc);
            const int cx = (int)xf;
            const int cy = (int)yf;
            const float fx = xc - xf;
            const float fy = yc - yf;
            const bool ok = (((unsigned)(cx - 1 - lox) < spanx) &
                             ((unsigned)(cy - 1 - loy) < spany));
            const int cxc = min(max(cx, 0), 65);
            const int cyc = min(max(cy, 0), 64);         // +TPITCH row stays <= 65
            const float* p = tile + cyc * TPITCH + cxc;
            const float v00 = p[0],      v10 = p[1];
            const float v01 = p[TPITCH], v11 = p[TPITCH + 1];
            const float top = fmaf(fx, v10 - v00, v00);
            const float bot = fmaf(fx, v11 - v01, v01);
            const float smp = fmaf(fy, bot - top, top);
            acc += ok ? smp : 0.0f;
            xc += step_x; yc += step_y;
        }
        if (acc != 0.0f && d <= dhi)
            atomicAdd(sacc + sbase + d, acc);
    }
}

// ---------------------------------------------------------------------------
// Kernel 2: pixel-driven exact adjoint, 4 y-pixels per thread, incremental
// (dc,tc) across the pixel quad, weight folded in, atomicAdd into out
// (pre-initialized to input by fwd). No bounds checks (dc in [0.5,254.5]).
// ---------------------------------------------------------------------------
__global__ __launch_bounds__(256, 8)
void bwd_partial_kernel(const float* __restrict__ sacc,
                        const float* __restrict__ proj,
                        const float* __restrict__ weight,
                        float* __restrict__ out) {
    __shared__ float s_t[NV * DD];
    __shared__ float4 s_g[NV];
    __shared__ float2 s_gd[NV];
    const int tid = threadIdx.x;
    const int v0 = blockIdx.y * NV;
    const int b  = (int)blockIdx.x >> 6;          // 64 blocks (1024 px) per image

    if (tid < NV) {
        float sn, cs;
        sincosf(view_angle(v0 + tid), &sn, &cs);
        s_g[tid]  = make_float4(cs, sn, F_SIG * cs, F_SIG * sn);
        s_gd[tid] = make_float2(F_DDY * cs, F_DDY * sn);
    }
    {   // stage s_t = DT*sacc - proj : NV*DD/4 = 768 float4 chunks
        const int base = (b * VV + v0) << 8;
        const float4* s4 = (const float4*)(sacc + base);
        const float4* p4 = (const float4*)(proj + base);
#pragma unroll
        for (int k = 0; k < NV * (DD / 4) / 256; ++k) {
            const int i = tid + (k << 8);
            const float4 a = s4[i];
            const float4 p = p4[i];
            float4 r;
            r.x = fmaf(F_DT, a.x, -p.x);
            r.y = fmaf(F_DT, a.y, -p.y);
            r.z = fmaf(F_DT, a.z, -p.z);
            r.w = fmaf(F_DT, a.w, -p.w);
            ((float4*)s_t)[i] = r;
        }
    }
    __syncthreads();

    const int idx = ((int)blockIdx.x << 10) + tid;    // pixel k at idx + k*256
    const int y0 = (idx >> 8) & 255;
    const int x  = idx & 255;
    const float xw  = (float)x  * (1.0f / 128.0f) + (0.5f / 128.0f - 1.0f);
    const float yw0 = (float)y0 * (1.0f / 128.0f) + (0.5f / 128.0f - 1.0f);

    float acc[4] = {0.f, 0.f, 0.f, 0.f};
#pragma unroll 2
    for (int vi = 0; vi < NV; ++vi) {
        const float4 g  = s_g[vi];                // cs, sn, A=sig*cs, B=sig*sn
        const float2 gd = s_gd[vi];               // ddc, dtc per pixel row
        const float* __restrict__ row = s_t + (vi << 8);
        const float sw = fmaf(-xw, g.y, yw0 * g.x);
        const float tw = fmaf( xw, g.x, yw0 * g.y);
        float dc = fmaf(sw, F_INV_DS, 127.5f);
        float tc = fmaf(tw, F_INV_DS, 127.5f);
#pragma unroll
        for (int k = 0; k < 4; ++k) {
            const float d0f = floorf(dc);
            const float t0f = floorf(tc);
            const int d0 = (int)d0f;
            const float fd = dc - d0f;
            const float ft = tc - t0f;

            const float dx00 = fmaf(g.z, -ft, g.w * fd);
            const float dyn  = fmaf(g.z,  fd, g.w * ft);
            const float dx01 = dx00 + g.z;
            const float dy01 = g.w - dyn;
            const float dx10 = dx00 - g.w;
            const float dy10 = g.z - dyn;
            const float dx11 = dx01 - g.w;
            const float dy11 = dy10 + g.w;

            const float w00 = fmaxf(0.0f, 1.0f - fabsf(dx00)) * fmaxf(0.0f, 1.0f - fabsf(dyn));
            const float w01 = fmaxf(0.0f, 1.0f - fabsf(dx01)) * fmaxf(0.0f, 1.0f - fabsf(dy01));
            const float w10 = fmaxf(0.0f, 1.0f - fabsf(dx10)) * fmaxf(0.0f, 1.0f - fabsf(dy10));
            const float w11 = fmaxf(0.0f, 1.0f - fabsf(dx11)) * fmaxf(0.0f, 1.0f - fabsf(dy11));

            acc[k] = fmaf(w00 + w01, row[d0],     acc[k]);
            acc[k] = fmaf(w10 + w11, row[d0 + 1], acc[k]);
            dc += gd.x; tc += gd.y;
        }
    }

    const float c = -weight[0] * F_DT;
#pragma unroll
    for (int k = 0; k < 4; ++k)
        atomicAdd(out + idx + (k << 8), c * acc[k]);
}

extern "C" void kernel_launch(void* const* d_in, const int* in_sizes, int n_in,
                              void* d_out, int out_size, void* d_ws, size_t ws_size,
                              hipStream_t stream) {
    const float* input  = (const float*)d_in[0];   // [nb, H, W]
    const float* proj   = (const float*)d_in[1];   // [nb, V, D]
    const float* weight = (const float*)d_in[2];   // [1]
    float* out  = (float*)d_out;                   // [nb, H, W]
    float* sacc = (float*)d_ws;                    // [nb, V, D] forward accumulator

    const int nb = in_sizes[0] / (HH * WW);        // B*C = 2
    const int npix = nb * HH * WW;
    const int nsino4 = nb * VV * DD / 4;

    init_kernel<<<(nsino4 + 255) / 256, 256, 0, stream>>>(sacc, nsino4);
    fwd_tile_kernel<<<dim3(16, VV, nb), 256, 0, stream>>>(input, sacc, out, npix / 4);
    bwd_partial_kernel<<<dim3(npix / 1024, NSEG), 256, 0, stream>>>(sacc, proj, weight, out);
}